// Round 9
// baseline (2125.390 us; speedup 1.0000x reference)
//
#include <hip/hip_runtime.h>
#include <math.h>

#define B_SZ 2048
#define SEQ 64
#define H 512
#define G4 2048
#define HH 256
#define NE 8
#define HOR 8

typedef _Float16 v8h __attribute__((ext_vector_type(8)));
typedef _Float16 v4h __attribute__((ext_vector_type(4)));
typedef float v4f __attribute__((ext_vector_type(4)));

__device__ __forceinline__ void gld16(const void* g, void* l) {
    __builtin_amdgcn_global_load_lds((const __attribute__((address_space(1))) void*)g,
                                     (__attribute__((address_space(3))) void*)l, 16, 0, 0);
}
__device__ __forceinline__ v4f mfma16(v8h a, v8h b, v4f c) {
    return __builtin_amdgcn_mfma_f32_16x16x32_f16(a, b, c, 0, 0, 0);
}
__device__ __forceinline__ float rcp_(float x) { return __builtin_amdgcn_rcpf(x); }
__device__ __forceinline__ float sigf(float x) { return rcp_(1.f + __expf(-x)); }
__device__ __forceinline__ float tanhf_(float x) { return 1.f - 2.f * rcp_(1.f + __expf(2.f * x)); }

// Fragment-chunk layout: operand stored as [chunk16rows][ktile][lane64][8];
// chunk[l*8+j] = M[c*16 + (l&15)][kt*32 + (l>>4)*8 + j].

struct CellP {
    const _Float16* Af; int KTA;       // A frag buffer, its total k-tiles
    const _Float16* Bf;                // weight frag buffer (dense, KT tiles)
    const float* bias; int KT;         // K-loop tiles
    float* cst;
    _Float16* h1p; int h1kt, h1o;      // dest buffers (frag layout)
    _Float16* h2p; int h2kt, h2o;
    const _Float16* xsrc; _Float16* xdst;   // x-copy into xdst (18-tile buf, ktile 16)
};

// Cell GEMM: block 64x128, 2 waves (wave tile 64x64), BK=32, dbuf staging.
// 128-thread blocks -> 4 blocks/CU on the 1024-block merged encoder grid:
// 4 independent barrier domains per CU hide each other's vmcnt drains
// (R8's 256-thread/2-per-CU config had only one partner block).
__global__ __launch_bounds__(128, 2)
void cell2_k(CellP P0, CellP P1, int zbase)
{
    __shared__ __align__(16) char smem[34816];   // max(2*12KB staging, 64*132*4 zb)
    const CellP& P = (blockIdx.z + zbase == 0) ? P0 : P1;
    _Float16* st = (_Float16*)smem;
    float* zb = (float*)smem;
    const int tid = threadIdx.x, lane = tid & 63, wv = tid >> 6;   // wv 0..1
    const int bx = blockIdx.x, by = blockIdx.y;                    // 64-row tiles
    const int KT = P.KT;

    // staging list: entries 0..3 = A chunks (row-chunks by*4+j), 4..11 = B chunks
    // (col-chunks bx*8+j). Wave wv stages entries [wv*6, wv*6+6).
    const _Float16* src[6];
    #pragma unroll
    for (int e = 0; e < 6; ++e) {
        int g = wv * 6 + e;
        if (g < 4) src[e] = P.Af + ((long)(by * 4 + g) * P.KTA) * 512 + lane * 8;
        else       src[e] = P.Bf + ((long)(bx * 8 + (g - 4)) * KT) * 512 + lane * 8;
    }
    const int fr = lane & 15, q4 = (lane >> 4) * 4;

    v4f acc[4][4];
    #pragma unroll
    for (int i = 0; i < 4; i++)
        #pragma unroll
        for (int j = 0; j < 4; j++) acc[i][j] = (v4f){0.f, 0.f, 0.f, 0.f};

    auto stage = [&](int buf) {
        _Float16* d = st + buf * 6144;
        #pragma unroll
        for (int e = 0; e < 6; ++e) {
            gld16(src[e], d + (wv * 6 + e) * 512);
            src[e] += 512;
        }
    };

    stage(0);
    for (int kt = 0; kt < KT; ++kt) {
        __syncthreads();                 // drains vmcnt -> staged tile visible
        if (kt + 1 < KT) stage((kt & 1) ^ 1);
        const _Float16* base = st + (kt & 1) * 6144;
        v8h bf[4];
        #pragma unroll
        for (int nt = 0; nt < 4; ++nt)
            bf[nt] = *(const v8h*)(base + (4 + wv * 4 + nt) * 512 + lane * 8);
        #pragma unroll
        for (int mt = 0; mt < 4; ++mt) {
            v8h a = *(const v8h*)(base + mt * 512 + lane * 8);
            #pragma unroll
            for (int nt = 0; nt < 4; ++nt)
                acc[mt][nt] = mfma16(a, bf[nt], acc[mt][nt]);
        }
    }

    // ---- cell epilogue (zb unions with staging) ----
    __syncthreads();
    #pragma unroll
    for (int mt = 0; mt < 4; ++mt)
        #pragma unroll
        for (int nt = 0; nt < 4; ++nt) {
            int col = wv * 64 + nt * 16 + fr;                 // 0..127
            float bv = P.bias[bx * 128 + col];
            #pragma unroll
            for (int r = 0; r < 4; ++r)
                zb[(mt * 16 + q4 + r) * 132 + col] = acc[mt][nt][r] + bv;
        }
    __syncthreads();
    {
        const int row = tid >> 1, u16 = (tid & 1) * 16;
        const long b = (long)by * 64 + row;
        float* cp = P.cst + b * 512 + bx * 32 + u16;
        float cv[16] __attribute__((aligned(16)));
        #pragma unroll
        for (int q = 0; q < 4; ++q) *(float4*)&cv[q * 4] = *(const float4*)(cp + q * 4);
        v8h hv[2];
        #pragma unroll
        for (int i = 0; i < 16; ++i) {
            const float* zz = &zb[row * 132 + (u16 + i) * 4];
            float cn = sigf(zz[1]) * cv[i] + sigf(zz[0]) * tanhf_(zz[2]);
            cv[i] = cn;
            hv[i >> 3][i & 7] = (_Float16)(sigf(zz[3]) * tanhf_(cn));
        }
        #pragma unroll
        for (int q = 0; q < 4; ++q) *(float4*)(cp + q * 4) = *(const float4*)&cv[q * 4];
        #pragma unroll
        for (int half = 0; half < 2; ++half) {
            int kk = P.h1o + bx * 32 + u16 + half * 8;
            long a = ((b >> 4) * (long)P.h1kt + (kk >> 5)) * 512 + (((kk & 31) >> 3) * 16 + (b & 15)) * 8;
            *(v8h*)(P.h1p + a) = hv[half];
        }
        if (P.h2p) {
            #pragma unroll
            for (int half = 0; half < 2; ++half) {
                int kk = P.h2o + bx * 32 + u16 + half * 8;
                long a = ((b >> 4) * (long)P.h2kt + (kk >> 5)) * 512 + (((kk & 31) >> 3) * 16 + (b & 15)) * 8;
                *(v8h*)(P.h2p + a) = hv[half];
            }
        }
        if (P.xsrc != nullptr && bx == 0) {
            int mc = by * 4 + (tid >> 5), l = tid & 31;
            v8h xv = *(const v8h*)(P.xsrc + ((long)mc * 32 + l) * 8);
            *(v8h*)(P.xdst + ((long)mc * 18 + 16) * 512 + l * 8) = xv;
        }
    }
}

// Expert layer-1 (+fused relu & layer-2 partial) for z<24; head slab z==24 -> t1.
__global__ __launch_bounds__(256, 4)
void expert_k(const _Float16* __restrict__ Af, const _Float16* __restrict__ W1f,
              const float* __restrict__ b1, const float* __restrict__ w2all,
              float* __restrict__ pe, _Float16* __restrict__ t1)
{
    __shared__ __align__(16) char smem[32768];
    _Float16* st = (_Float16*)smem;
    float* red = (float*)smem;
    const int tid = threadIdx.x, lane = tid & 63, wv = tid >> 6;
    const int bx = blockIdx.x, by = blockIdx.y;
    const long z = blockIdx.z;

    const _Float16* pA0 = Af + ((long)(by * 8 + 2 * wv) * 18) * 512 + lane * 8;
    const _Float16* pA1 = Af + ((long)(by * 8 + 2 * wv + 1) * 18) * 512 + lane * 8;
    const _Float16* pB0 = W1f + ((z * 16 + bx * 8 + 2 * wv) * 16) * 512 + lane * 8;
    const _Float16* pB1 = W1f + ((z * 16 + bx * 8 + 2 * wv + 1) * 16) * 512 + lane * 8;
    const int oA0 = 2 * wv * 512, oA1 = oA0 + 512;
    const int oB0 = 4096 + 2 * wv * 512, oB1 = oB0 + 512;
    const int wm = (wv & 1) * 64, wn = (wv >> 1) * 64;
    const int fr = lane & 15, q4 = (lane >> 4) * 4;

    v4f acc[4][4];
    #pragma unroll
    for (int i = 0; i < 4; i++)
        #pragma unroll
        for (int j = 0; j < 4; j++) acc[i][j] = (v4f){0.f, 0.f, 0.f, 0.f};

    gld16(pA0, st + oA0); gld16(pA1, st + oA1);
    gld16(pB0, st + oB0); gld16(pB1, st + oB1);
    pA0 += 512; pA1 += 512; pB0 += 512; pB1 += 512;

    for (int kt = 0; kt < 16; ++kt) {
        __syncthreads();
        const int cur = kt & 1;
        if (kt + 1 < 16) {
            _Float16* nb = st + (cur ^ 1) * 8192;
            gld16(pA0, nb + oA0); gld16(pA1, nb + oA1);
            gld16(pB0, nb + oB0); gld16(pB1, nb + oB1);
            pA0 += 512; pA1 += 512; pB0 += 512; pB1 += 512;
        }
        const _Float16* base = st + cur * 8192;
        v8h bf[4];
        #pragma unroll
        for (int nt = 0; nt < 4; ++nt)
            bf[nt] = *(const v8h*)(base + 4096 + ((wv >> 1) * 4 + nt) * 512 + lane * 8);
        #pragma unroll
        for (int mt = 0; mt < 4; ++mt) {
            v8h a = *(const v8h*)(base + ((wv & 1) * 4 + mt) * 512 + lane * 8);
            #pragma unroll
            for (int nt = 0; nt < 4; ++nt)
                acc[mt][nt] = mfma16(a, bf[nt], acc[mt][nt]);
        }
    }
    __syncthreads();

    if (z == 24) {     // head -> t1 (2048 x 256 fp16 row-major)
        #pragma unroll
        for (int mt = 0; mt < 4; ++mt)
            #pragma unroll
            for (int nt = 0; nt < 4; ++nt) {
                int col = bx * 128 + wn + nt * 16 + fr;
                float bv = b1[24 * 256 + col];
                #pragma unroll
                for (int r = 0; r < 4; ++r) {
                    float v = fmaxf(acc[mt][nt][r] + bv, 0.f);
                    t1[(long)(by * 128 + wm + mt * 16 + q4 + r) * 256 + col] = (_Float16)v;
                }
            }
        return;
    }
    float w0[4], w1[4], bv[4];
    #pragma unroll
    for (int nt = 0; nt < 4; ++nt) {
        int col = bx * 128 + wn + nt * 16 + fr;
        w0[nt] = w2all[(z * 2 + 0) * 256 + col];
        w1[nt] = w2all[(z * 2 + 1) * 256 + col];
        bv[nt] = b1[z * 256 + col];
    }
    float p0[4][4], p1[4][4];
    #pragma unroll
    for (int mt = 0; mt < 4; ++mt)
        #pragma unroll
        for (int r = 0; r < 4; ++r) { p0[mt][r] = 0.f; p1[mt][r] = 0.f; }
    #pragma unroll
    for (int mt = 0; mt < 4; ++mt)
        #pragma unroll
        for (int nt = 0; nt < 4; ++nt)
            #pragma unroll
            for (int r = 0; r < 4; ++r) {
                float v = fmaxf(acc[mt][nt][r] + bv[nt], 0.f);
                p0[mt][r] = fmaf(v, w0[nt], p0[mt][r]);
                p1[mt][r] = fmaf(v, w1[nt], p1[mt][r]);
            }
    #pragma unroll
    for (int off = 1; off < 16; off <<= 1)
        #pragma unroll
        for (int mt = 0; mt < 4; ++mt)
            #pragma unroll
            for (int r = 0; r < 4; ++r) {
                p0[mt][r] += __shfl_xor(p0[mt][r], off, 64);
                p1[mt][r] += __shfl_xor(p1[mt][r], off, 64);
            }
    if ((lane & 15) == 0) {
        #pragma unroll
        for (int mt = 0; mt < 4; ++mt)
            #pragma unroll
            for (int r = 0; r < 4; ++r) {
                int rw = wm + mt * 16 + q4 + r;
                red[(((wv >> 1) * 128) + rw) * 2 + 0] = p0[mt][r];
                red[(((wv >> 1) * 128) + rw) * 2 + 1] = p1[mt][r];
            }
    }
    __syncthreads();
    if (tid < 128) {
        #pragma unroll
        for (int o = 0; o < 2; ++o) {
            float v = red[tid * 2 + o] + red[(128 + tid) * 2 + o];
            pe[(((long)bx * 24 + z) * 2 + o) * 2048 + by * 128 + tid] = v;
        }
    }
}

// Gates softmax + gates_avg + gated expert combine + outputs + dec_in.
__global__ __launch_bounds__(256)
void fin_k(const _Float16* __restrict__ t1, const float* __restrict__ gW2,
           const float* __restrict__ gb2, const float* __restrict__ pe,
           const float* __restrict__ tb2, const float* __restrict__ ib2,
           const float* __restrict__ wb2,
           float* __restrict__ out, _Float16* __restrict__ dw, int step)
{
    const long b = blockIdx.x * 256 + threadIdx.x;
    float acc[NE];
    #pragma unroll
    for (int e = 0; e < NE; e++) acc[e] = gb2[e];
    for (int j = 0; j < 256; j += 8) {
        v8h tv = *(const v8h*)(t1 + b * 256 + j);
        #pragma unroll
        for (int k = 0; k < 8; ++k) {
            float xv = (float)tv[k];
            #pragma unroll
            for (int e = 0; e < NE; e++) acc[e] = fmaf(xv, gW2[e * 256 + j + k], acc[e]);
        }
    }
    float mx = -1e30f;
    #pragma unroll
    for (int e = 0; e < NE; e++) mx = fmaxf(mx, acc[e]);
    float s = 0.f;
    #pragma unroll
    for (int e = 0; e < NE; e++) { acc[e] = __expf(acc[e] - mx); s += acc[e]; }
    float inv = 1.f / s;
    float t0 = 0.f, t1v = 0.f, iv = 0.f, wvv = 0.f;
    #pragma unroll
    for (int e = 0; e < NE; e++) {
        float g = acc[e] * inv;
        float prev = step == 0 ? 0.f : out[32 * (long)B_SZ + b * NE + e];
        out[32 * (long)B_SZ + b * NE + e] = prev + g * (1.f / HOR);
        float s00 = pe[((0 * 24 + e) * 2 + 0) * 2048 + b] + pe[((1 * 24 + e) * 2 + 0) * 2048 + b];
        float s01 = pe[((0 * 24 + e) * 2 + 1) * 2048 + b] + pe[((1 * 24 + e) * 2 + 1) * 2048 + b];
        float s10 = pe[((0 * 24 + 8 + e) * 2 + 0) * 2048 + b] + pe[((1 * 24 + 8 + e) * 2 + 0) * 2048 + b];
        float s20 = pe[((0 * 24 + 16 + e) * 2 + 0) * 2048 + b] + pe[((1 * 24 + 16 + e) * 2 + 0) * 2048 + b];
        t0  += g * (s00 + tb2[e * 2 + 0]);
        t1v += g * (s01 + tb2[e * 2 + 1]);
        iv  += g * (s10 + ib2[e]);
        wvv += g * (s20 + wb2[e]);
    }
    out[b * 16 + step] = t0;
    out[b * 16 + 8 + step] = t1v;
    out[16 * (long)B_SZ + b * 8 + step] = iv;
    out[24 * (long)B_SZ + b * 8 + step] = wvv;
    v4h dv = {(_Float16)t0, (_Float16)t1v, (_Float16)iv, (_Float16)wvv};
    *(v4h*)(dw + ((b >> 4) * 18 + 16) * 512 + (b & 15) * 8) = dv;
}

// Gate-interleaved cell weights -> fragment-chunk layout (+ interleaved bias).
__global__ __launch_bounds__(64)
void prep_wfrag(const float* __restrict__ s1, int K1, const float* __restrict__ s2, int K2,
                _Float16* __restrict__ dst, int KT,
                const float* __restrict__ bs, float* __restrict__ bd)
{
    const int nc = blockIdx.x, kt = blockIdx.y, l = threadIdx.x;
    const int nprime = nc * 16 + (l & 15);
    const int u = nprime >> 2, g = nprime & 3, srow = g * 512 + u;
    v8h v;
    #pragma unroll
    for (int j = 0; j < 8; ++j) {
        int k = kt * 32 + (l >> 4) * 8 + j;
        float val = 0.f;
        if (k < K1) val = s1[(long)srow * K1 + k];
        else if (k < K1 + K2) val = s2[(long)srow * K2 + k - K1];
        v[j] = (_Float16)val;
    }
    *(v8h*)(dst + ((long)nc * KT + kt) * 512 + l * 8) = v;
    if (kt == 0 && l < 16) bd[nc * 16 + l] = bs[((nc * 16 + l) & 3) * 512 + ((nc * 16 + l) >> 2)];
}

__global__ __launch_bounds__(64)
void prep_w1frag(const float* __restrict__ tW1, const float* __restrict__ iW1,
                 const float* __restrict__ wW1, const float* __restrict__ gW1,
                 _Float16* __restrict__ dst)
{
    const int nc = blockIdx.x & 15, kt = blockIdx.x >> 4, z = blockIdx.y, l = threadIdx.x;
    const float* src;
    if (z < 8) src = tW1 + (long)z * 256 * 512;
    else if (z < 16) src = iW1 + (long)(z - 8) * 256 * 512;
    else if (z < 24) src = wW1 + (long)(z - 16) * 256 * 512;
    else src = gW1;
    const int row = nc * 16 + (l & 15);
    v8h v;
    #pragma unroll
    for (int j = 0; j < 8; ++j)
        v[j] = (_Float16)src[(long)row * 512 + kt * 32 + (l >> 4) * 8 + j];
    *(v8h*)(dst + (((long)z * 16 + nc) * 16 + kt) * 512 + l * 8) = v;
}

__global__ __launch_bounds__(256)
void cat4(const float* __restrict__ a, const float* __restrict__ b,
          const float* __restrict__ c, const float* __restrict__ g,
          float* __restrict__ d)
{
    int i = blockIdx.x * 256 + threadIdx.x;   // < 6400
    float v;
    if (i < 2048) v = a[i];
    else if (i < 4096) v = b[i - 2048];
    else if (i < 6144) v = c[i - 4096];
    else v = g[i - 6144];
    d[i] = v;
}

__global__ __launch_bounds__(256)
void prep_w2(const float* __restrict__ tW2, const float* __restrict__ iW2,
             const float* __restrict__ wW2, float* __restrict__ W2all)
{
    int i = blockIdx.x * 256 + threadIdx.x;   // < 24*2*256
    int j = i & 255, o = (i >> 8) & 1, zz = i >> 9;
    int br = zz >> 3, e = zz & 7;
    float v = 0.f;
    if (br == 0) v = tW2[(e * 2 + o) * 256 + j];
    else if (o == 0) v = (br == 1 ? iW2 : wW2)[e * 256 + j];
    W2all[i] = v;
}

// x (B,S,16) -> per-step fragment chunks xTf[s][mc][l(32)][8]; seed act0a ktile16.
__global__ __launch_bounds__(256)
void prep_xf(const float* __restrict__ x, _Float16* __restrict__ xTf,
             _Float16* __restrict__ act0a)
{
    const int t = blockIdx.x * 256 + threadIdx.x;   // < 64*128*32
    const int l = t & 31, mc = (t >> 5) & 127, s = t >> 12;
    const long b = mc * 16 + (l & 15);
    const float* src = x + (b * 64 + s) * 16 + (l >> 4) * 8;
    v8h v;
    #pragma unroll
    for (int j = 0; j < 8; ++j) v[j] = (_Float16)src[j];
    *(v8h*)(xTf + (((long)s * 128 + mc) * 32 + l) * 8) = v;
    if (s == 0) *(v8h*)(act0a + ((long)mc * 18 + 16) * 512 + l * 8) = v;
}

extern "C" void kernel_launch(void* const* d_in, const int* in_sizes, int n_in,
                              void* d_out, int out_size, void* d_ws, size_t ws_size,
                              hipStream_t stream)
{
    const float* x    = (const float*)d_in[0];
    const float* Wih0 = (const float*)d_in[1];
    const float* Whh0 = (const float*)d_in[2];
    const float* b0   = (const float*)d_in[3];
    const float* Wih1 = (const float*)d_in[4];
    const float* Whh1 = (const float*)d_in[5];
    const float* b1   = (const float*)d_in[6];
    const float* dWih = (const float*)d_in[7];
    const float* dWhh = (const float*)d_in[8];
    const float* db   = (const float*)d_in[9];
    const float* gW1  = (const float*)d_in[10];
    const float* gb1  = (const float*)d_in[11];
    const float* gW2  = (const float*)d_in[12];
    const float* gb2  = (const float*)d_in[13];
    const float* tW1  = (const float*)d_in[14];
    const float* tb1  = (const float*)d_in[15];
    const float* tW2  = (const float*)d_in[16];
    const float* tb2  = (const float*)d_in[17];
    const float* iW1  = (const float*)d_in[18];
    const float* ib1  = (const float*)d_in[19];
    const float* iW2  = (const float*)d_in[20];
    const float* ib2  = (const float*)d_in[21];
    const float* wW1  = (const float*)d_in[22];
    const float* wb1  = (const float*)d_in[23];
    const float* wW2  = (const float*)d_in[24];
    const float* wb2  = (const float*)d_in[25];
    float* out = (float*)d_out;

    char* p = (char*)d_ws;
    auto alloc = [&](size_t bytes) { char* r = p; p += (bytes + 255) & ~255ULL; return r; };
    _Float16* xTf   = (_Float16*)alloc((size_t)SEQ * 128 * 32 * 8 * 2);
    _Float16* act0a = (_Float16*)alloc((size_t)128 * 18 * 512 * 2);
    _Float16* act0b = (_Float16*)alloc((size_t)128 * 18 * 512 * 2);
    _Float16* act1a = (_Float16*)alloc((size_t)128 * 32 * 512 * 2);
    _Float16* act1b = (_Float16*)alloc((size_t)128 * 32 * 512 * 2);
    _Float16* actDa = (_Float16*)alloc((size_t)128 * 18 * 512 * 2);
    _Float16* actDb = (_Float16*)alloc((size_t)128 * 18 * 512 * 2);
    float*    c0    = (float*)alloc((size_t)B_SZ * 512 * 4);
    float*    c1    = (float*)alloc((size_t)B_SZ * 512 * 4);
    _Float16* Wc0   = (_Float16*)alloc((size_t)128 * 18 * 512 * 2);
    _Float16* Wc1   = (_Float16*)alloc((size_t)128 * 32 * 512 * 2);
    _Float16* Wcd   = (_Float16*)alloc((size_t)128 * 18 * 512 * 2);
    float*    b0i   = (float*)alloc((size_t)G4 * 4);
    float*    b1i   = (float*)alloc((size_t)G4 * 4);
    float*    bdi   = (float*)alloc((size_t)G4 * 4);
    _Float16* W1all = (_Float16*)alloc((size_t)25 * 16 * 16 * 512 * 2);
    float*    b1all = (float*)alloc((size_t)25 * HH * 4);
    float*    W2all = (float*)alloc((size_t)24 * 2 * 256 * 4);
    _Float16* t1    = (_Float16*)alloc((size_t)B_SZ * HH * 2);
    float*    pe    = (float*)alloc((size_t)2 * 24 * 2 * 2048 * 4);

    hipMemsetAsync(act0a, 0, (size_t)128 * 18 * 512 * 2, stream);
    hipMemsetAsync(act0b, 0, (size_t)128 * 18 * 512 * 2, stream);
    hipMemsetAsync(act1a, 0, (size_t)128 * 32 * 512 * 2, stream);
    hipMemsetAsync(act1b, 0, (size_t)128 * 32 * 512 * 2, stream);
    hipMemsetAsync(actDa, 0, (size_t)128 * 18 * 512 * 2, stream);
    hipMemsetAsync(actDb, 0, (size_t)128 * 18 * 512 * 2, stream);
    hipMemsetAsync(c0, 0, (size_t)B_SZ * 512 * 4, stream);
    hipMemsetAsync(c1, 0, (size_t)B_SZ * 512 * 4, stream);

    prep_wfrag<<<dim3(128, 18), dim3(64), 0, stream>>>(Whh0, 512, Wih0, 16, Wc0, 18, b0, b0i);
    prep_wfrag<<<dim3(128, 32), dim3(64), 0, stream>>>(Wih1, 512, Whh1, 512, Wc1, 32, b1, b1i);
    prep_wfrag<<<dim3(128, 18), dim3(64), 0, stream>>>(dWhh, 512, dWih, 4, Wcd, 18, db, bdi);
    prep_w1frag<<<dim3(256, 25), dim3(64), 0, stream>>>(tW1, iW1, wW1, gW1, W1all);
    cat4<<<dim3(25), dim3(256), 0, stream>>>(tb1, ib1, wb1, gb1, b1all);
    prep_w2<<<dim3(48), dim3(256), 0, stream>>>(tW2, iW2, wW2, W2all);
    prep_xf<<<dim3(1024), dim3(256), 0, stream>>>(x, xTf, act0a);

    _Float16* act0[2] = {act0a, act0b};
    _Float16* act1[2] = {act1a, act1b};

    // ----- encoder: merged launch s runs L0_s and L1_{s-1}; 1024 blocks = 4/CU -----
    for (int s = 0; s <= SEQ; ++s) {
        const bool do0 = (s < SEQ), do1 = (s >= 1);
        CellP P0 = {}, P1 = {};
        if (do0) {
            P0.Af = act0[s & 1]; P0.KTA = 18;
            P0.Bf = Wc0; P0.bias = b0i; P0.KT = 18;
            P0.cst = c0;
            P0.h1p = act0[(s + 1) & 1]; P0.h1kt = 18; P0.h1o = 0;
            P0.h2p = act1[s & 1]; P0.h2kt = 32; P0.h2o = 0;
            P0.xsrc = (s < SEQ - 1) ? (xTf + ((long)(s + 1) * 128 * 32) * 8) : nullptr;
            P0.xdst = act0[(s + 1) & 1];
        }
        if (do1) {
            P1.Af = act1[(s + 1) & 1]; P1.KTA = 32;
            P1.Bf = Wc1; P1.bias = b1i; P1.KT = 32;
            P1.cst = c1;
            P1.h1p = act1[s & 1]; P1.h1kt = 32; P1.h1o = 512;
            P1.h2p = (s == SEQ) ? actDa : nullptr; P1.h2kt = 18; P1.h2o = 0;
            P1.xsrc = nullptr; P1.xdst = nullptr;
        }
        const int nz = (do0 && do1) ? 2 : 1;
        const int zbase = do0 ? 0 : 1;
        cell2_k<<<dim3(16, 32, nz), dim3(128), 0, stream>>>(P0, P1, zbase);
    }

    // ----- decoder: 8 steps x 3 launches -----
    for (int t = 0; t < HOR; ++t) {
        _Float16* dr = (t & 1) ? actDb : actDa;
        _Float16* dw = (t & 1) ? actDa : actDb;
        CellP PD = {};
        PD.Af = dr; PD.KTA = 18;
        PD.Bf = Wcd; PD.bias = bdi; PD.KT = 18;
        PD.cst = c1;
        PD.h1p = dw; PD.h1kt = 18; PD.h1o = 0;
        PD.h2p = nullptr; PD.xsrc = nullptr; PD.xdst = nullptr;
        cell2_k<<<dim3(16, 32, 1), dim3(128), 0, stream>>>(PD, PD, 0);
        expert_k<<<dim3(2, 16, 25), dim3(256), 0, stream>>>(dw, W1all, b1all, W2all, pe, t1);
        fin_k<<<dim3(8), dim3(256), 0, stream>>>(t1, gW2, gb2, pe, tb2, ib2, wb2, out, dw, t);
    }
}

// Round 10
// 1996.099 us; speedup vs baseline: 1.0648x; 1.0648x over previous
//
#include <hip/hip_runtime.h>
#include <math.h>

#define B_SZ 2048
#define SEQ 64
#define H 512
#define G4 2048
#define HH 256
#define NE 8
#define HOR 8

typedef _Float16 v8h __attribute__((ext_vector_type(8)));
typedef _Float16 v4h __attribute__((ext_vector_type(4)));
typedef float v4f __attribute__((ext_vector_type(4)));

__device__ __forceinline__ void gld16(const void* g, void* l) {
    __builtin_amdgcn_global_load_lds((const __attribute__((address_space(1))) void*)g,
                                     (__attribute__((address_space(3))) void*)l, 16, 0, 0);
}
__device__ __forceinline__ v4f mfma16(v8h a, v8h b, v4f c) {
    return __builtin_amdgcn_mfma_f32_16x16x32_f16(a, b, c, 0, 0, 0);
}
__device__ __forceinline__ float rcp_(float x) { return __builtin_amdgcn_rcpf(x); }
__device__ __forceinline__ float sigf(float x) { return rcp_(1.f + __expf(-x)); }
__device__ __forceinline__ float tanhf_(float x) { return 1.f - 2.f * rcp_(1.f + __expf(2.f * x)); }

// Fragment-chunk layout: operand stored as [chunk16rows][ktile][lane64][8];
// chunk[l*8+j] = M[c*16 + (l&15)][kt*32 + (l>>4)*8 + j].
// Cell GEMM K padded to a multiple of 64 (18 ktiles) -> BK=64 loop, no tail.

struct CellP {
    const _Float16* Af; int KTA;       // A frag buffer, its total k-tiles (even)
    const _Float16* Bf;                // weight frag buffer (dense, KT tiles)
    const float* bias; int KT;         // K-loop tiles (even)
    float* cst;
    _Float16* h1p; int h1kt, h1o;      // dest buffers (frag layout)
    _Float16* h2p; int h2kt, h2o;
    const _Float16* xsrc; _Float16* xdst;   // x-copy into xdst (18-tile buf, ktile 16)
};

// Block 128x128, 4 waves (2x2), wave tile 64x64, BK=64, dbuf (R8 structure).
// 1D grid + XCD swizzle: flat id f -> xcd = f%8 (dispatch round-robin
// heuristic); each XCD owns by in {2*xcd, 2*xcd+1} for BOTH layers and all
// 16 bx, so A-chunk re-reads (16x per chunk) are L2-local to one XCD and
// weights settle L2-resident per XCD across the 64 steps.
__global__ __launch_bounds__(256, 2)
void cell2_k(CellP P0, CellP P1, int zbase)
{
    __shared__ __align__(16) char smem[65536];
    const int f = blockIdx.x;
    const int xcd = f & 7;
    const int r = f >> 3;
    const int by = (xcd << 1) | (r & 1);
    const int rr = r >> 1;
    const int bx = rr & 15;
    const int z = rr >> 4;                    // 0 when grid==256
    const CellP& P = (z + zbase == 0) ? P0 : P1;
    _Float16* st = (_Float16*)smem;
    float* zb = (float*)smem;                 // 128 x 68 fp32 (union after K-loop)
    const int tid = threadIdx.x, lane = tid & 63, wv = tid >> 6;
    const int NIT = P.KT >> 1;                // 64-k iterations

    const _Float16* pA0 = P.Af + ((long)(by * 8 + 2 * wv) * P.KTA) * 512 + lane * 8;
    const _Float16* pA1 = P.Af + ((long)(by * 8 + 2 * wv + 1) * P.KTA) * 512 + lane * 8;
    const _Float16* pB0 = P.Bf + ((long)(bx * 8 + 2 * wv) * P.KT) * 512 + lane * 8;
    const _Float16* pB1 = P.Bf + ((long)(bx * 8 + 2 * wv + 1) * P.KT) * 512 + lane * 8;
    const int oA = 4 * wv * 512;              // LDS chunk offsets (wave-uniform)
    const int oB = 8192 + 4 * wv * 512;
    const int wm = (wv & 1) * 64;
    const int fr = lane & 15, q4 = (lane >> 4) * 4;

    v4f acc[4][4];
    #pragma unroll
    for (int i = 0; i < 4; i++)
        #pragma unroll
        for (int j = 0; j < 4; j++) acc[i][j] = (v4f){0.f, 0.f, 0.f, 0.f};

    auto stage = [&](int buf, int it) {
        _Float16* d = st + buf * 16384;
        const long ko = (long)it * 1024;      // 2 ktiles = 1024 elements
        gld16(pA0 + ko,       d + oA);
        gld16(pA0 + ko + 512, d + oA + 512);
        gld16(pA1 + ko,       d + oA + 1024);
        gld16(pA1 + ko + 512, d + oA + 1536);
        gld16(pB0 + ko,       d + oB);
        gld16(pB0 + ko + 512, d + oB + 512);
        gld16(pB1 + ko,       d + oB + 1024);
        gld16(pB1 + ko + 512, d + oB + 1536);
    };

    stage(0, 0);
    for (int it = 0; it < NIT; ++it) {
        __syncthreads();                       // drains vmcnt -> staged tiles visible
        if (it + 1 < NIT) stage((it & 1) ^ 1, it + 1);
        const _Float16* base = st + (it & 1) * 16384;
        #pragma unroll
        for (int p = 0; p < 2; ++p) {          // sub-ktile within the 64-k tile
            v8h bf[4];
            #pragma unroll
            for (int nt = 0; nt < 4; ++nt)
                bf[nt] = *(const v8h*)(base + 8192 + (((wv >> 1) * 4 + nt) * 2 + p) * 512 + lane * 8);
            #pragma unroll
            for (int mt = 0; mt < 4; ++mt) {
                v8h a = *(const v8h*)(base + (((wv & 1) * 4 + mt) * 2 + p) * 512 + lane * 8);
                #pragma unroll
                for (int nt = 0; nt < 4; ++nt)
                    acc[mt][nt] = mfma16(a, bf[nt], acc[mt][nt]);
            }
        }
    }

    // ---- cell epilogue, two 64-col halves (zb unions with staging) ----
    #pragma unroll
    for (int half = 0; half < 2; ++half) {
        __syncthreads();
        if ((wv >> 1) == half) {
            #pragma unroll
            for (int mt = 0; mt < 4; ++mt)
                #pragma unroll
                for (int nt = 0; nt < 4; ++nt) {
                    int col = nt * 16 + fr;                      // 0..63 within half
                    float bv = P.bias[bx * 128 + half * 64 + col];
                    #pragma unroll
                    for (int r2 = 0; r2 < 4; ++r2)
                        zb[(wm + mt * 16 + q4 + r2) * 68 + col] = acc[mt][nt][r2] + bv;
                }
        }
        __syncthreads();
        const int row = tid >> 1, u8 = (tid & 1) * 8;
        const long b = by * 128 + row;
        const int ug = bx * 32 + half * 16 + u8;
        float* cp = P.cst + b * 512 + ug;
        float4 cl0 = *(float4*)cp, cl1 = *(float4*)(cp + 4);
        float cv[8] = {cl0.x, cl0.y, cl0.z, cl0.w, cl1.x, cl1.y, cl1.z, cl1.w};
        v8h hv;
        #pragma unroll
        for (int i = 0; i < 8; ++i) {
            const float* zz = &zb[row * 68 + (u8 + i) * 4];
            float cn = sigf(zz[1]) * cv[i] + sigf(zz[0]) * tanhf_(zz[2]);
            cv[i] = cn;
            hv[i] = (_Float16)(sigf(zz[3]) * tanhf_(cn));
        }
        *(float4*)cp = make_float4(cv[0], cv[1], cv[2], cv[3]);
        *(float4*)(cp + 4) = make_float4(cv[4], cv[5], cv[6], cv[7]);
        {
            int kk = P.h1o + ug;
            long a = ((b >> 4) * (long)P.h1kt + (kk >> 5)) * 512 + (((kk & 31) >> 3) * 16 + (b & 15)) * 8;
            *(v8h*)(P.h1p + a) = hv;
        }
        if (P.h2p) {
            int kk = P.h2o + ug;
            long a = ((b >> 4) * (long)P.h2kt + (kk >> 5)) * 512 + (((kk & 31) >> 3) * 16 + (b & 15)) * 8;
            *(v8h*)(P.h2p + a) = hv;
        }
        if (half == 0 && P.xsrc != nullptr && bx == 0) {
            int mc = tid >> 5, l = tid & 31;
            v8h xv = *(const v8h*)(P.xsrc + ((long)(by * 8 + mc) * 32 + l) * 8);
            *(v8h*)(P.xdst + (((long)(by * 8 + mc)) * 18 + 16) * 512 + l * 8) = xv;
        }
    }
}

// Expert layer-1 (+fused relu & layer-2 partial) for z<24; head slab z==24 -> t1.
__global__ __launch_bounds__(256, 4)
void expert_k(const _Float16* __restrict__ Af, const _Float16* __restrict__ W1f,
              const float* __restrict__ b1, const float* __restrict__ w2all,
              float* __restrict__ pe, _Float16* __restrict__ t1)
{
    __shared__ __align__(16) char smem[32768];
    _Float16* st = (_Float16*)smem;
    float* red = (float*)smem;
    const int tid = threadIdx.x, lane = tid & 63, wv = tid >> 6;
    const int bx = blockIdx.x, by = blockIdx.y;
    const long z = blockIdx.z;

    const _Float16* pA0 = Af + ((long)(by * 8 + 2 * wv) * 18) * 512 + lane * 8;
    const _Float16* pA1 = Af + ((long)(by * 8 + 2 * wv + 1) * 18) * 512 + lane * 8;
    const _Float16* pB0 = W1f + ((z * 16 + bx * 8 + 2 * wv) * 16) * 512 + lane * 8;
    const _Float16* pB1 = W1f + ((z * 16 + bx * 8 + 2 * wv + 1) * 16) * 512 + lane * 8;
    const int oA0 = 2 * wv * 512, oA1 = oA0 + 512;
    const int oB0 = 4096 + 2 * wv * 512, oB1 = oB0 + 512;
    const int wm = (wv & 1) * 64, wn = (wv >> 1) * 64;
    const int fr = lane & 15, q4 = (lane >> 4) * 4;

    v4f acc[4][4];
    #pragma unroll
    for (int i = 0; i < 4; i++)
        #pragma unroll
        for (int j = 0; j < 4; j++) acc[i][j] = (v4f){0.f, 0.f, 0.f, 0.f};

    gld16(pA0, st + oA0); gld16(pA1, st + oA1);
    gld16(pB0, st + oB0); gld16(pB1, st + oB1);
    pA0 += 512; pA1 += 512; pB0 += 512; pB1 += 512;

    for (int kt = 0; kt < 16; ++kt) {
        __syncthreads();
        const int cur = kt & 1;
        if (kt + 1 < 16) {
            _Float16* nb = st + (cur ^ 1) * 8192;
            gld16(pA0, nb + oA0); gld16(pA1, nb + oA1);
            gld16(pB0, nb + oB0); gld16(pB1, nb + oB1);
            pA0 += 512; pA1 += 512; pB0 += 512; pB1 += 512;
        }
        const _Float16* base = st + cur * 8192;
        v8h bf[4];
        #pragma unroll
        for (int nt = 0; nt < 4; ++nt)
            bf[nt] = *(const v8h*)(base + 4096 + ((wv >> 1) * 4 + nt) * 512 + lane * 8);
        #pragma unroll
        for (int mt = 0; mt < 4; ++mt) {
            v8h a = *(const v8h*)(base + ((wv & 1) * 4 + mt) * 512 + lane * 8);
            #pragma unroll
            for (int nt = 0; nt < 4; ++nt)
                acc[mt][nt] = mfma16(a, bf[nt], acc[mt][nt]);
        }
    }
    __syncthreads();

    if (z == 24) {     // head -> t1 (2048 x 256 fp16 row-major)
        #pragma unroll
        for (int mt = 0; mt < 4; ++mt)
            #pragma unroll
            for (int nt = 0; nt < 4; ++nt) {
                int col = bx * 128 + wn + nt * 16 + fr;
                float bv = b1[24 * 256 + col];
                #pragma unroll
                for (int r = 0; r < 4; ++r) {
                    float v = fmaxf(acc[mt][nt][r] + bv, 0.f);
                    t1[(long)(by * 128 + wm + mt * 16 + q4 + r) * 256 + col] = (_Float16)v;
                }
            }
        return;
    }
    float w0[4], w1[4], bv[4];
    #pragma unroll
    for (int nt = 0; nt < 4; ++nt) {
        int col = bx * 128 + wn + nt * 16 + fr;
        w0[nt] = w2all[(z * 2 + 0) * 256 + col];
        w1[nt] = w2all[(z * 2 + 1) * 256 + col];
        bv[nt] = b1[z * 256 + col];
    }
    float p0[4][4], p1[4][4];
    #pragma unroll
    for (int mt = 0; mt < 4; ++mt)
        #pragma unroll
        for (int r = 0; r < 4; ++r) { p0[mt][r] = 0.f; p1[mt][r] = 0.f; }
    #pragma unroll
    for (int mt = 0; mt < 4; ++mt)
        #pragma unroll
        for (int nt = 0; nt < 4; ++nt)
            #pragma unroll
            for (int r = 0; r < 4; ++r) {
                float v = fmaxf(acc[mt][nt][r] + bv[nt], 0.f);
                p0[mt][r] = fmaf(v, w0[nt], p0[mt][r]);
                p1[mt][r] = fmaf(v, w1[nt], p1[mt][r]);
            }
    #pragma unroll
    for (int off = 1; off < 16; off <<= 1)
        #pragma unroll
        for (int mt = 0; mt < 4; ++mt)
            #pragma unroll
            for (int r = 0; r < 4; ++r) {
                p0[mt][r] += __shfl_xor(p0[mt][r], off, 64);
                p1[mt][r] += __shfl_xor(p1[mt][r], off, 64);
            }
    if ((lane & 15) == 0) {
        #pragma unroll
        for (int mt = 0; mt < 4; ++mt)
            #pragma unroll
            for (int r = 0; r < 4; ++r) {
                int rw = wm + mt * 16 + q4 + r;
                red[(((wv >> 1) * 128) + rw) * 2 + 0] = p0[mt][r];
                red[(((wv >> 1) * 128) + rw) * 2 + 1] = p1[mt][r];
            }
    }
    __syncthreads();
    if (tid < 128) {
        #pragma unroll
        for (int o = 0; o < 2; ++o) {
            float v = red[tid * 2 + o] + red[(128 + tid) * 2 + o];
            pe[(((long)bx * 24 + z) * 2 + o) * 2048 + by * 128 + tid] = v;
        }
    }
}

// Gates softmax + gates_avg + gated expert combine + outputs + dec_in.
__global__ __launch_bounds__(256)
void fin_k(const _Float16* __restrict__ t1, const float* __restrict__ gW2,
           const float* __restrict__ gb2, const float* __restrict__ pe,
           const float* __restrict__ tb2, const float* __restrict__ ib2,
           const float* __restrict__ wb2,
           float* __restrict__ out, _Float16* __restrict__ dw, int step)
{
    const long b = blockIdx.x * 256 + threadIdx.x;
    float acc[NE];
    #pragma unroll
    for (int e = 0; e < NE; e++) acc[e] = gb2[e];
    for (int j = 0; j < 256; j += 8) {
        v8h tv = *(const v8h*)(t1 + b * 256 + j);
        #pragma unroll
        for (int k = 0; k < 8; ++k) {
            float xv = (float)tv[k];
            #pragma unroll
            for (int e = 0; e < NE; e++) acc[e] = fmaf(xv, gW2[e * 256 + j + k], acc[e]);
        }
    }
    float mx = -1e30f;
    #pragma unroll
    for (int e = 0; e < NE; e++) mx = fmaxf(mx, acc[e]);
    float s = 0.f;
    #pragma unroll
    for (int e = 0; e < NE; e++) { acc[e] = __expf(acc[e] - mx); s += acc[e]; }
    float inv = 1.f / s;
    float t0 = 0.f, t1v = 0.f, iv = 0.f, wvv = 0.f;
    #pragma unroll
    for (int e = 0; e < NE; e++) {
        float g = acc[e] * inv;
        float prev = step == 0 ? 0.f : out[32 * (long)B_SZ + b * NE + e];
        out[32 * (long)B_SZ + b * NE + e] = prev + g * (1.f / HOR);
        float s00 = pe[((0 * 24 + e) * 2 + 0) * 2048 + b] + pe[((1 * 24 + e) * 2 + 0) * 2048 + b];
        float s01 = pe[((0 * 24 + e) * 2 + 1) * 2048 + b] + pe[((1 * 24 + e) * 2 + 1) * 2048 + b];
        float s10 = pe[((0 * 24 + 8 + e) * 2 + 0) * 2048 + b] + pe[((1 * 24 + 8 + e) * 2 + 0) * 2048 + b];
        float s20 = pe[((0 * 24 + 16 + e) * 2 + 0) * 2048 + b] + pe[((1 * 24 + 16 + e) * 2 + 0) * 2048 + b];
        t0  += g * (s00 + tb2[e * 2 + 0]);
        t1v += g * (s01 + tb2[e * 2 + 1]);
        iv  += g * (s10 + ib2[e]);
        wvv += g * (s20 + wb2[e]);
    }
    out[b * 16 + step] = t0;
    out[b * 16 + 8 + step] = t1v;
    out[16 * (long)B_SZ + b * 8 + step] = iv;
    out[24 * (long)B_SZ + b * 8 + step] = wvv;
    v4h dv = {(_Float16)t0, (_Float16)t1v, (_Float16)iv, (_Float16)wvv};
    *(v4h*)(dw + ((b >> 4) * 18 + 16) * 512 + (b & 15) * 8) = dv;
}

// Gate-interleaved cell weights -> fragment-chunk layout (+ interleaved bias).
__global__ __launch_bounds__(64)
void prep_wfrag(const float* __restrict__ s1, int K1, const float* __restrict__ s2, int K2,
                _Float16* __restrict__ dst, int KT,
                const float* __restrict__ bs, float* __restrict__ bd)
{
    const int nc = blockIdx.x, kt = blockIdx.y, l = threadIdx.x;
    const int nprime = nc * 16 + (l & 15);
    const int u = nprime >> 2, g = nprime & 3, srow = g * 512 + u;
    v8h v;
    #pragma unroll
    for (int j = 0; j < 8; ++j) {
        int k = kt * 32 + (l >> 4) * 8 + j;
        float val = 0.f;
        if (k < K1) val = s1[(long)srow * K1 + k];
        else if (k < K1 + K2) val = s2[(long)srow * K2 + k - K1];
        v[j] = (_Float16)val;
    }
    *(v8h*)(dst + ((long)nc * KT + kt) * 512 + l * 8) = v;
    if (kt == 0 && l < 16) bd[nc * 16 + l] = bs[((nc * 16 + l) & 3) * 512 + ((nc * 16 + l) >> 2)];
}

__global__ __launch_bounds__(64)
void prep_w1frag(const float* __restrict__ tW1, const float* __restrict__ iW1,
                 const float* __restrict__ wW1, const float* __restrict__ gW1,
                 _Float16* __restrict__ dst)
{
    const int nc = blockIdx.x & 15, kt = blockIdx.x >> 4, z = blockIdx.y, l = threadIdx.x;
    const float* src;
    if (z < 8) src = tW1 + (long)z * 256 * 512;
    else if (z < 16) src = iW1 + (long)(z - 8) * 256 * 512;
    else if (z < 24) src = wW1 + (long)(z - 16) * 256 * 512;
    else src = gW1;
    const int row = nc * 16 + (l & 15);
    v8h v;
    #pragma unroll
    for (int j = 0; j < 8; ++j)
        v[j] = (_Float16)src[(long)row * 512 + kt * 32 + (l >> 4) * 8 + j];
    *(v8h*)(dst + (((long)z * 16 + nc) * 16 + kt) * 512 + l * 8) = v;
}

__global__ __launch_bounds__(256)
void cat4(const float* __restrict__ a, const float* __restrict__ b,
          const float* __restrict__ c, const float* __restrict__ g,
          float* __restrict__ d)
{
    int i = blockIdx.x * 256 + threadIdx.x;   // < 6400
    float v;
    if (i < 2048) v = a[i];
    else if (i < 4096) v = b[i - 2048];
    else if (i < 6144) v = c[i - 4096];
    else v = g[i - 6144];
    d[i] = v;
}

__global__ __launch_bounds__(256)
void prep_w2(const float* __restrict__ tW2, const float* __restrict__ iW2,
             const float* __restrict__ wW2, float* __restrict__ W2all)
{
    int i = blockIdx.x * 256 + threadIdx.x;   // < 24*2*256
    int j = i & 255, o = (i >> 8) & 1, zz = i >> 9;
    int br = zz >> 3, e = zz & 7;
    float v = 0.f;
    if (br == 0) v = tW2[(e * 2 + o) * 256 + j];
    else if (o == 0) v = (br == 1 ? iW2 : wW2)[e * 256 + j];
    W2all[i] = v;
}

// x (B,S,16) -> per-step fragment chunks xTf[s][mc][l(32)][8]; seed act0a ktile16.
__global__ __launch_bounds__(256)
void prep_xf(const float* __restrict__ x, _Float16* __restrict__ xTf,
             _Float16* __restrict__ act0a)
{
    const int t = blockIdx.x * 256 + threadIdx.x;   // < 64*128*32
    const int l = t & 31, mc = (t >> 5) & 127, s = t >> 12;
    const long b = mc * 16 + (l & 15);
    const float* src = x + (b * 64 + s) * 16 + (l >> 4) * 8;
    v8h v;
    #pragma unroll
    for (int j = 0; j < 8; ++j) v[j] = (_Float16)src[j];
    *(v8h*)(xTf + (((long)s * 128 + mc) * 32 + l) * 8) = v;
    if (s == 0) *(v8h*)(act0a + ((long)mc * 18 + 16) * 512 + l * 8) = v;
}

extern "C" void kernel_launch(void* const* d_in, const int* in_sizes, int n_in,
                              void* d_out, int out_size, void* d_ws, size_t ws_size,
                              hipStream_t stream)
{
    const float* x    = (const float*)d_in[0];
    const float* Wih0 = (const float*)d_in[1];
    const float* Whh0 = (const float*)d_in[2];
    const float* b0   = (const float*)d_in[3];
    const float* Wih1 = (const float*)d_in[4];
    const float* Whh1 = (const float*)d_in[5];
    const float* b1   = (const float*)d_in[6];
    const float* dWih = (const float*)d_in[7];
    const float* dWhh = (const float*)d_in[8];
    const float* db   = (const float*)d_in[9];
    const float* gW1  = (const float*)d_in[10];
    const float* gb1  = (const float*)d_in[11];
    const float* gW2  = (const float*)d_in[12];
    const float* gb2  = (const float*)d_in[13];
    const float* tW1  = (const float*)d_in[14];
    const float* tb1  = (const float*)d_in[15];
    const float* tW2  = (const float*)d_in[16];
    const float* tb2  = (const float*)d_in[17];
    const float* iW1  = (const float*)d_in[18];
    const float* ib1  = (const float*)d_in[19];
    const float* iW2  = (const float*)d_in[20];
    const float* ib2  = (const float*)d_in[21];
    const float* wW1  = (const float*)d_in[22];
    const float* wb1  = (const float*)d_in[23];
    const float* wW2  = (const float*)d_in[24];
    const float* wb2  = (const float*)d_in[25];
    float* out = (float*)d_out;

    char* p = (char*)d_ws;
    auto alloc = [&](size_t bytes) { char* r = p; p += (bytes + 255) & ~255ULL; return r; };
    _Float16* xTf   = (_Float16*)alloc((size_t)SEQ * 128 * 32 * 8 * 2);
    _Float16* act0a = (_Float16*)alloc((size_t)128 * 18 * 512 * 2);
    _Float16* act0b = (_Float16*)alloc((size_t)128 * 18 * 512 * 2);
    _Float16* act1a = (_Float16*)alloc((size_t)128 * 32 * 512 * 2);
    _Float16* act1b = (_Float16*)alloc((size_t)128 * 32 * 512 * 2);
    _Float16* actDa = (_Float16*)alloc((size_t)128 * 18 * 512 * 2);
    _Float16* actDb = (_Float16*)alloc((size_t)128 * 18 * 512 * 2);
    float*    c0    = (float*)alloc((size_t)B_SZ * 512 * 4);
    float*    c1    = (float*)alloc((size_t)B_SZ * 512 * 4);
    _Float16* Wc0   = (_Float16*)alloc((size_t)128 * 18 * 512 * 2);
    _Float16* Wc1   = (_Float16*)alloc((size_t)128 * 32 * 512 * 2);
    _Float16* Wcd   = (_Float16*)alloc((size_t)128 * 18 * 512 * 2);
    float*    b0i   = (float*)alloc((size_t)G4 * 4);
    float*    b1i   = (float*)alloc((size_t)G4 * 4);
    float*    bdi   = (float*)alloc((size_t)G4 * 4);
    _Float16* W1all = (_Float16*)alloc((size_t)25 * 16 * 16 * 512 * 2);
    float*    b1all = (float*)alloc((size_t)25 * HH * 4);
    float*    W2all = (float*)alloc((size_t)24 * 2 * 256 * 4);
    _Float16* t1    = (_Float16*)alloc((size_t)B_SZ * HH * 2);
    float*    pe    = (float*)alloc((size_t)2 * 24 * 2 * 2048 * 4);

    hipMemsetAsync(act0a, 0, (size_t)128 * 18 * 512 * 2, stream);
    hipMemsetAsync(act0b, 0, (size_t)128 * 18 * 512 * 2, stream);
    hipMemsetAsync(act1a, 0, (size_t)128 * 32 * 512 * 2, stream);
    hipMemsetAsync(act1b, 0, (size_t)128 * 32 * 512 * 2, stream);
    hipMemsetAsync(actDa, 0, (size_t)128 * 18 * 512 * 2, stream);
    hipMemsetAsync(actDb, 0, (size_t)128 * 18 * 512 * 2, stream);
    hipMemsetAsync(c0, 0, (size_t)B_SZ * 512 * 4, stream);
    hipMemsetAsync(c1, 0, (size_t)B_SZ * 512 * 4, stream);

    prep_wfrag<<<dim3(128, 18), dim3(64), 0, stream>>>(Whh0, 512, Wih0, 16, Wc0, 18, b0, b0i);
    prep_wfrag<<<dim3(128, 32), dim3(64), 0, stream>>>(Wih1, 512, Whh1, 512, Wc1, 32, b1, b1i);
    prep_wfrag<<<dim3(128, 18), dim3(64), 0, stream>>>(dWhh, 512, dWih, 4, Wcd, 18, db, bdi);
    prep_w1frag<<<dim3(256, 25), dim3(64), 0, stream>>>(tW1, iW1, wW1, gW1, W1all);
    cat4<<<dim3(25), dim3(256), 0, stream>>>(tb1, ib1, wb1, gb1, b1all);
    prep_w2<<<dim3(48), dim3(256), 0, stream>>>(tW2, iW2, wW2, W2all);
    prep_xf<<<dim3(1024), dim3(256), 0, stream>>>(x, xTf, act0a);

    _Float16* act0[2] = {act0a, act0b};
    _Float16* act1[2] = {act1a, act1b};

    // ----- encoder: merged launch s runs L0_s and L1_{s-1}; flat XCD-swizzled grid -----
    for (int s = 0; s <= SEQ; ++s) {
        const bool do0 = (s < SEQ), do1 = (s >= 1);
        CellP P0 = {}, P1 = {};
        if (do0) {
            P0.Af = act0[s & 1]; P0.KTA = 18;
            P0.Bf = Wc0; P0.bias = b0i; P0.KT = 18;
            P0.cst = c0;
            P0.h1p = act0[(s + 1) & 1]; P0.h1kt = 18; P0.h1o = 0;
            P0.h2p = act1[s & 1]; P0.h2kt = 32; P0.h2o = 0;
            P0.xsrc = (s < SEQ - 1) ? (xTf + ((long)(s + 1) * 128 * 32) * 8) : nullptr;
            P0.xdst = act0[(s + 1) & 1];
        }
        if (do1) {
            P1.Af = act1[(s + 1) & 1]; P1.KTA = 32;
            P1.Bf = Wc1; P1.bias = b1i; P1.KT = 32;
            P1.cst = c1;
            P1.h1p = act1[s & 1]; P1.h1kt = 32; P1.h1o = 512;
            P1.h2p = (s == SEQ) ? actDa : nullptr; P1.h2kt = 18; P1.h2o = 0;
            P1.xsrc = nullptr; P1.xdst = nullptr;
        }
        const int nz = (do0 && do1) ? 2 : 1;
        const int zbase = do0 ? 0 : 1;
        cell2_k<<<dim3(256 * nz), dim3(256), 0, stream>>>(P0, P1, zbase);
    }

    // ----- decoder: 8 steps x 3 launches -----
    for (int t = 0; t < HOR; ++t) {
        _Float16* dr = (t & 1) ? actDb : actDa;
        _Float16* dw = (t & 1) ? actDa : actDb;
        CellP PD = {};
        PD.Af = dr; PD.KTA = 18;
        PD.Bf = Wcd; PD.bias = bdi; PD.KT = 18;
        PD.cst = c1;
        PD.h1p = dw; PD.h1kt = 18; PD.h1o = 0;
        PD.h2p = nullptr; PD.xsrc = nullptr; PD.xdst = nullptr;
        cell2_k<<<dim3(256), dim3(256), 0, stream>>>(PD, PD, 0);
        expert_k<<<dim3(2, 16, 25), dim3(256), 0, stream>>>(dw, W1all, b1all, W2all, pe, t1);
        fin_k<<<dim3(8), dim3(256), 0, stream>>>(t1, gW2, gb2, pe, tb2, ib2, wb2, out, dw, t);
    }
}

// Round 11
// 1929.594 us; speedup vs baseline: 1.1015x; 1.0345x over previous
//
#include <hip/hip_runtime.h>
#include <math.h>

#define B_SZ 2048
#define SEQ 64
#define H 512
#define G4 2048
#define HH 256
#define NE 8
#define HOR 8

typedef _Float16 v8h __attribute__((ext_vector_type(8)));
typedef _Float16 v4h __attribute__((ext_vector_type(4)));
typedef float v4f __attribute__((ext_vector_type(4)));

__device__ __forceinline__ void gld16(const void* g, void* l) {
    __builtin_amdgcn_global_load_lds((const __attribute__((address_space(1))) void*)g,
                                     (__attribute__((address_space(3))) void*)l, 16, 0, 0);
}
__device__ __forceinline__ v4f mfma16(v8h a, v8h b, v4f c) {
    return __builtin_amdgcn_mfma_f32_16x16x32_f16(a, b, c, 0, 0, 0);
}
__device__ __forceinline__ float rcp_(float x) { return __builtin_amdgcn_rcpf(x); }
__device__ __forceinline__ float sigf(float x) { return rcp_(1.f + __expf(-x)); }
__device__ __forceinline__ float tanhf_(float x) { return 1.f - 2.f * rcp_(1.f + __expf(2.f * x)); }

// Fragment-chunk layout: operand stored as [chunk16rows][ktile][lane64][8];
// chunk[l*8+j] = M[c*16 + (l&15)][kt*32 + (l>>4)*8 + j].
// Cell GEMM K padded to a multiple of 64 (18 ktiles for K=544+pad) so the
// BK=64 double-tile loop has no tail; pad tiles are zeros (bitwise-neutral).

struct CellP {
    const _Float16* Af; int KTA;       // A frag buffer, its total k-tiles (even)
    const _Float16* Bf;                // weight frag buffer (dense, KT tiles)
    const float* bias; int KT;         // K-loop tiles (even)
    float* cst;
    _Float16* h1p; int h1kt, h1o;      // dest buffers (frag layout)
    _Float16* h2p; int h2kt, h2o;
    const _Float16* xsrc; _Float16* xdst;   // x-copy into xdst (18-tile buf, ktile 16)
};

// Block 128x128, 4 waves (2x2), wave tile 64x64, BK=64 (2 ktiles/iter),
// double-buffered staging (32 KB per buffer, 64 KB LDS -> 2 blocks/CU,
// which the merged grid (512 blocks) is limited to anyway).
// R8 configuration — measured optimum: BK=32 (+100us), 2-wave TLP split
// (+152us), XCD swizzle (+23us) all verified worse; explicit finer
// pipelining neutral. Do not re-tweak without new counter evidence.
__global__ __launch_bounds__(256, 2)
void cell2_k(CellP P0, CellP P1, int zbase)
{
    __shared__ __align__(16) char smem[65536];
    const CellP& P = (blockIdx.z + zbase == 0) ? P0 : P1;
    _Float16* st = (_Float16*)smem;
    float* zb = (float*)smem;                 // 128 x 68 fp32 (union after K-loop)
    const int tid = threadIdx.x, lane = tid & 63, wv = tid >> 6;
    const int bx = blockIdx.x, by = blockIdx.y;
    const int NIT = P.KT >> 1;                // 64-k iterations

    const _Float16* pA0 = P.Af + ((long)(by * 8 + 2 * wv) * P.KTA) * 512 + lane * 8;
    const _Float16* pA1 = P.Af + ((long)(by * 8 + 2 * wv + 1) * P.KTA) * 512 + lane * 8;
    const _Float16* pB0 = P.Bf + ((long)(bx * 8 + 2 * wv) * P.KT) * 512 + lane * 8;
    const _Float16* pB1 = P.Bf + ((long)(bx * 8 + 2 * wv + 1) * P.KT) * 512 + lane * 8;
    const int oA = 4 * wv * 512;              // LDS chunk offsets (wave-uniform)
    const int oB = 8192 + 4 * wv * 512;
    const int wm = (wv & 1) * 64;
    const int fr = lane & 15, q4 = (lane >> 4) * 4;

    v4f acc[4][4];
    #pragma unroll
    for (int i = 0; i < 4; i++)
        #pragma unroll
        for (int j = 0; j < 4; j++) acc[i][j] = (v4f){0.f, 0.f, 0.f, 0.f};

    auto stage = [&](int buf, int it) {
        _Float16* d = st + buf * 16384;
        const long ko = (long)it * 1024;      // 2 ktiles = 1024 elements
        gld16(pA0 + ko,       d + oA);
        gld16(pA0 + ko + 512, d + oA + 512);
        gld16(pA1 + ko,       d + oA + 1024);
        gld16(pA1 + ko + 512, d + oA + 1536);
        gld16(pB0 + ko,       d + oB);
        gld16(pB0 + ko + 512, d + oB + 512);
        gld16(pB1 + ko,       d + oB + 1024);
        gld16(pB1 + ko + 512, d + oB + 1536);
    };

    stage(0, 0);
    for (int it = 0; it < NIT; ++it) {
        __syncthreads();                       // drains vmcnt -> staged tiles visible
        if (it + 1 < NIT) stage((it & 1) ^ 1, it + 1);
        const _Float16* base = st + (it & 1) * 16384;
        #pragma unroll
        for (int p = 0; p < 2; ++p) {          // sub-ktile within the 64-k tile
            v8h bf[4];
            #pragma unroll
            for (int nt = 0; nt < 4; ++nt)
                bf[nt] = *(const v8h*)(base + 8192 + (((wv >> 1) * 4 + nt) * 2 + p) * 512 + lane * 8);
            #pragma unroll
            for (int mt = 0; mt < 4; ++mt) {
                v8h a = *(const v8h*)(base + (((wv & 1) * 4 + mt) * 2 + p) * 512 + lane * 8);
                #pragma unroll
                for (int nt = 0; nt < 4; ++nt)
                    acc[mt][nt] = mfma16(a, bf[nt], acc[mt][nt]);
            }
        }
    }

    // ---- cell epilogue, two 64-col halves (zb unions with staging) ----
    #pragma unroll
    for (int half = 0; half < 2; ++half) {
        __syncthreads();
        if ((wv >> 1) == half) {
            #pragma unroll
            for (int mt = 0; mt < 4; ++mt)
                #pragma unroll
                for (int nt = 0; nt < 4; ++nt) {
                    int col = nt * 16 + fr;                      // 0..63 within half
                    float bv = P.bias[bx * 128 + half * 64 + col];
                    #pragma unroll
                    for (int r = 0; r < 4; ++r)
                        zb[(wm + mt * 16 + q4 + r) * 68 + col] = acc[mt][nt][r] + bv;
                }
        }
        __syncthreads();
        const int row = tid >> 1, u8 = (tid & 1) * 8;
        const long b = by * 128 + row;
        const int ug = bx * 32 + half * 16 + u8;
        float* cp = P.cst + b * 512 + ug;
        float4 cl0 = *(float4*)cp, cl1 = *(float4*)(cp + 4);
        float cv[8] = {cl0.x, cl0.y, cl0.z, cl0.w, cl1.x, cl1.y, cl1.z, cl1.w};
        v8h hv;
        #pragma unroll
        for (int i = 0; i < 8; ++i) {
            const float* zz = &zb[row * 68 + (u8 + i) * 4];
            float cn = sigf(zz[1]) * cv[i] + sigf(zz[0]) * tanhf_(zz[2]);
            cv[i] = cn;
            hv[i] = (_Float16)(sigf(zz[3]) * tanhf_(cn));
        }
        *(float4*)cp = make_float4(cv[0], cv[1], cv[2], cv[3]);
        *(float4*)(cp + 4) = make_float4(cv[4], cv[5], cv[6], cv[7]);
        {
            int kk = P.h1o + ug;
            long a = ((b >> 4) * (long)P.h1kt + (kk >> 5)) * 512 + (((kk & 31) >> 3) * 16 + (b & 15)) * 8;
            *(v8h*)(P.h1p + a) = hv;
        }
        if (P.h2p) {
            int kk = P.h2o + ug;
            long a = ((b >> 4) * (long)P.h2kt + (kk >> 5)) * 512 + (((kk & 31) >> 3) * 16 + (b & 15)) * 8;
            *(v8h*)(P.h2p + a) = hv;
        }
        if (half == 0 && P.xsrc != nullptr && bx == 0) {
            int mc = tid >> 5, l = tid & 31;
            v8h xv = *(const v8h*)(P.xsrc + ((long)(by * 8 + mc) * 32 + l) * 8);
            *(v8h*)(P.xdst + (((long)(by * 8 + mc)) * 18 + 16) * 512 + l * 8) = xv;
        }
    }
}

// Expert layer-1 (+fused relu & layer-2 partial) for z<24; head slab z==24 -> t1.
__global__ __launch_bounds__(256, 4)
void expert_k(const _Float16* __restrict__ Af, const _Float16* __restrict__ W1f,
              const float* __restrict__ b1, const float* __restrict__ w2all,
              float* __restrict__ pe, _Float16* __restrict__ t1)
{
    __shared__ __align__(16) char smem[32768];
    _Float16* st = (_Float16*)smem;
    float* red = (float*)smem;
    const int tid = threadIdx.x, lane = tid & 63, wv = tid >> 6;
    const int bx = blockIdx.x, by = blockIdx.y;
    const long z = blockIdx.z;

    const _Float16* pA0 = Af + ((long)(by * 8 + 2 * wv) * 18) * 512 + lane * 8;
    const _Float16* pA1 = Af + ((long)(by * 8 + 2 * wv + 1) * 18) * 512 + lane * 8;
    const _Float16* pB0 = W1f + ((z * 16 + bx * 8 + 2 * wv) * 16) * 512 + lane * 8;
    const _Float16* pB1 = W1f + ((z * 16 + bx * 8 + 2 * wv + 1) * 16) * 512 + lane * 8;
    const int oA0 = 2 * wv * 512, oA1 = oA0 + 512;
    const int oB0 = 4096 + 2 * wv * 512, oB1 = oB0 + 512;
    const int wm = (wv & 1) * 64, wn = (wv >> 1) * 64;
    const int fr = lane & 15, q4 = (lane >> 4) * 4;

    v4f acc[4][4];
    #pragma unroll
    for (int i = 0; i < 4; i++)
        #pragma unroll
        for (int j = 0; j < 4; j++) acc[i][j] = (v4f){0.f, 0.f, 0.f, 0.f};

    gld16(pA0, st + oA0); gld16(pA1, st + oA1);
    gld16(pB0, st + oB0); gld16(pB1, st + oB1);
    pA0 += 512; pA1 += 512; pB0 += 512; pB1 += 512;

    for (int kt = 0; kt < 16; ++kt) {
        __syncthreads();
        const int cur = kt & 1;
        if (kt + 1 < 16) {
            _Float16* nb = st + (cur ^ 1) * 8192;
            gld16(pA0, nb + oA0); gld16(pA1, nb + oA1);
            gld16(pB0, nb + oB0); gld16(pB1, nb + oB1);
            pA0 += 512; pA1 += 512; pB0 += 512; pB1 += 512;
        }
        const _Float16* base = st + cur * 8192;
        v8h bf[4];
        #pragma unroll
        for (int nt = 0; nt < 4; ++nt)
            bf[nt] = *(const v8h*)(base + 4096 + ((wv >> 1) * 4 + nt) * 512 + lane * 8);
        #pragma unroll
        for (int mt = 0; mt < 4; ++mt) {
            v8h a = *(const v8h*)(base + ((wv & 1) * 4 + mt) * 512 + lane * 8);
            #pragma unroll
            for (int nt = 0; nt < 4; ++nt)
                acc[mt][nt] = mfma16(a, bf[nt], acc[mt][nt]);
        }
    }
    __syncthreads();

    if (z == 24) {     // head -> t1 (2048 x 256 fp16 row-major)
        #pragma unroll
        for (int mt = 0; mt < 4; ++mt)
            #pragma unroll
            for (int nt = 0; nt < 4; ++nt) {
                int col = bx * 128 + wn + nt * 16 + fr;
                float bv = b1[24 * 256 + col];
                #pragma unroll
                for (int r = 0; r < 4; ++r) {
                    float v = fmaxf(acc[mt][nt][r] + bv, 0.f);
                    t1[(long)(by * 128 + wm + mt * 16 + q4 + r) * 256 + col] = (_Float16)v;
                }
            }
        return;
    }
    float w0[4], w1[4], bv[4];
    #pragma unroll
    for (int nt = 0; nt < 4; ++nt) {
        int col = bx * 128 + wn + nt * 16 + fr;
        w0[nt] = w2all[(z * 2 + 0) * 256 + col];
        w1[nt] = w2all[(z * 2 + 1) * 256 + col];
        bv[nt] = b1[z * 256 + col];
    }
    float p0[4][4], p1[4][4];
    #pragma unroll
    for (int mt = 0; mt < 4; ++mt)
        #pragma unroll
        for (int r = 0; r < 4; ++r) { p0[mt][r] = 0.f; p1[mt][r] = 0.f; }
    #pragma unroll
    for (int mt = 0; mt < 4; ++mt)
        #pragma unroll
        for (int nt = 0; nt < 4; ++nt)
            #pragma unroll
            for (int r = 0; r < 4; ++r) {
                float v = fmaxf(acc[mt][nt][r] + bv[nt], 0.f);
                p0[mt][r] = fmaf(v, w0[nt], p0[mt][r]);
                p1[mt][r] = fmaf(v, w1[nt], p1[mt][r]);
            }
    #pragma unroll
    for (int off = 1; off < 16; off <<= 1)
        #pragma unroll
        for (int mt = 0; mt < 4; ++mt)
            #pragma unroll
            for (int r = 0; r < 4; ++r) {
                p0[mt][r] += __shfl_xor(p0[mt][r], off, 64);
                p1[mt][r] += __shfl_xor(p1[mt][r], off, 64);
            }
    if ((lane & 15) == 0) {
        #pragma unroll
        for (int mt = 0; mt < 4; ++mt)
            #pragma unroll
            for (int r = 0; r < 4; ++r) {
                int rw = wm + mt * 16 + q4 + r;
                red[(((wv >> 1) * 128) + rw) * 2 + 0] = p0[mt][r];
                red[(((wv >> 1) * 128) + rw) * 2 + 1] = p1[mt][r];
            }
    }
    __syncthreads();
    if (tid < 128) {
        #pragma unroll
        for (int o = 0; o < 2; ++o) {
            float v = red[tid * 2 + o] + red[(128 + tid) * 2 + o];
            pe[(((long)bx * 24 + z) * 2 + o) * 2048 + by * 128 + tid] = v;
        }
    }
}

// Gates softmax + gates_avg + gated expert combine + outputs + dec_in.
__global__ __launch_bounds__(256)
void fin_k(const _Float16* __restrict__ t1, const float* __restrict__ gW2,
           const float* __restrict__ gb2, const float* __restrict__ pe,
           const float* __restrict__ tb2, const float* __restrict__ ib2,
           const float* __restrict__ wb2,
           float* __restrict__ out, _Float16* __restrict__ dw, int step)
{
    const long b = blockIdx.x * 256 + threadIdx.x;
    float acc[NE];
    #pragma unroll
    for (int e = 0; e < NE; e++) acc[e] = gb2[e];
    for (int j = 0; j < 256; j += 8) {
        v8h tv = *(const v8h*)(t1 + b * 256 + j);
        #pragma unroll
        for (int k = 0; k < 8; ++k) {
            float xv = (float)tv[k];
            #pragma unroll
            for (int e = 0; e < NE; e++) acc[e] = fmaf(xv, gW2[e * 256 + j + k], acc[e]);
        }
    }
    float mx = -1e30f;
    #pragma unroll
    for (int e = 0; e < NE; e++) mx = fmaxf(mx, acc[e]);
    float s = 0.f;
    #pragma unroll
    for (int e = 0; e < NE; e++) { acc[e] = __expf(acc[e] - mx); s += acc[e]; }
    float inv = 1.f / s;
    float t0 = 0.f, t1v = 0.f, iv = 0.f, wvv = 0.f;
    #pragma unroll
    for (int e = 0; e < NE; e++) {
        float g = acc[e] * inv;
        float prev = step == 0 ? 0.f : out[32 * (long)B_SZ + b * NE + e];
        out[32 * (long)B_SZ + b * NE + e] = prev + g * (1.f / HOR);
        float s00 = pe[((0 * 24 + e) * 2 + 0) * 2048 + b] + pe[((1 * 24 + e) * 2 + 0) * 2048 + b];
        float s01 = pe[((0 * 24 + e) * 2 + 1) * 2048 + b] + pe[((1 * 24 + e) * 2 + 1) * 2048 + b];
        float s10 = pe[((0 * 24 + 8 + e) * 2 + 0) * 2048 + b] + pe[((1 * 24 + 8 + e) * 2 + 0) * 2048 + b];
        float s20 = pe[((0 * 24 + 16 + e) * 2 + 0) * 2048 + b] + pe[((1 * 24 + 16 + e) * 2 + 0) * 2048 + b];
        t0  += g * (s00 + tb2[e * 2 + 0]);
        t1v += g * (s01 + tb2[e * 2 + 1]);
        iv  += g * (s10 + ib2[e]);
        wvv += g * (s20 + wb2[e]);
    }
    out[b * 16 + step] = t0;
    out[b * 16 + 8 + step] = t1v;
    out[16 * (long)B_SZ + b * 8 + step] = iv;
    out[24 * (long)B_SZ + b * 8 + step] = wvv;
    v4h dv = {(_Float16)t0, (_Float16)t1v, (_Float16)iv, (_Float16)wvv};
    *(v4h*)(dw + ((b >> 4) * 18 + 16) * 512 + (b & 15) * 8) = dv;
}

// Gate-interleaved cell weights -> fragment-chunk layout (+ interleaved bias).
__global__ __launch_bounds__(64)
void prep_wfrag(const float* __restrict__ s1, int K1, const float* __restrict__ s2, int K2,
                _Float16* __restrict__ dst, int KT,
                const float* __restrict__ bs, float* __restrict__ bd)
{
    const int nc = blockIdx.x, kt = blockIdx.y, l = threadIdx.x;
    const int nprime = nc * 16 + (l & 15);
    const int u = nprime >> 2, g = nprime & 3, srow = g * 512 + u;
    v8h v;
    #pragma unroll
    for (int j = 0; j < 8; ++j) {
        int k = kt * 32 + (l >> 4) * 8 + j;
        float val = 0.f;
        if (k < K1) val = s1[(long)srow * K1 + k];
        else if (k < K1 + K2) val = s2[(long)srow * K2 + k - K1];
        v[j] = (_Float16)val;
    }
    *(v8h*)(dst + ((long)nc * KT + kt) * 512 + l * 8) = v;
    if (kt == 0 && l < 16) bd[nc * 16 + l] = bs[((nc * 16 + l) & 3) * 512 + ((nc * 16 + l) >> 2)];
}

__global__ __launch_bounds__(64)
void prep_w1frag(const float* __restrict__ tW1, const float* __restrict__ iW1,
                 const float* __restrict__ wW1, const float* __restrict__ gW1,
                 _Float16* __restrict__ dst)
{
    const int nc = blockIdx.x & 15, kt = blockIdx.x >> 4, z = blockIdx.y, l = threadIdx.x;
    const float* src;
    if (z < 8) src = tW1 + (long)z * 256 * 512;
    else if (z < 16) src = iW1 + (long)(z - 8) * 256 * 512;
    else if (z < 24) src = wW1 + (long)(z - 16) * 256 * 512;
    else src = gW1;
    const int row = nc * 16 + (l & 15);
    v8h v;
    #pragma unroll
    for (int j = 0; j < 8; ++j)
        v[j] = (_Float16)src[(long)row * 512 + kt * 32 + (l >> 4) * 8 + j];
    *(v8h*)(dst + (((long)z * 16 + nc) * 16 + kt) * 512 + l * 8) = v;
}

__global__ __launch_bounds__(256)
void cat4(const float* __restrict__ a, const float* __restrict__ b,
          const float* __restrict__ c, const float* __restrict__ g,
          float* __restrict__ d)
{
    int i = blockIdx.x * 256 + threadIdx.x;   // < 6400
    float v;
    if (i < 2048) v = a[i];
    else if (i < 4096) v = b[i - 2048];
    else if (i < 6144) v = c[i - 4096];
    else v = g[i - 6144];
    d[i] = v;
}

__global__ __launch_bounds__(256)
void prep_w2(const float* __restrict__ tW2, const float* __restrict__ iW2,
             const float* __restrict__ wW2, float* __restrict__ W2all)
{
    int i = blockIdx.x * 256 + threadIdx.x;   // < 24*2*256
    int j = i & 255, o = (i >> 8) & 1, zz = i >> 9;
    int br = zz >> 3, e = zz & 7;
    float v = 0.f;
    if (br == 0) v = tW2[(e * 2 + o) * 256 + j];
    else if (o == 0) v = (br == 1 ? iW2 : wW2)[e * 256 + j];
    W2all[i] = v;
}

// x (B,S,16) -> per-step fragment chunks xTf[s][mc][l(32)][8]; seed act0a ktile16.
__global__ __launch_bounds__(256)
void prep_xf(const float* __restrict__ x, _Float16* __restrict__ xTf,
             _Float16* __restrict__ act0a)
{
    const int t = blockIdx.x * 256 + threadIdx.x;   // < 64*128*32
    const int l = t & 31, mc = (t >> 5) & 127, s = t >> 12;
    const long b = mc * 16 + (l & 15);
    const float* src = x + (b * 64 + s) * 16 + (l >> 4) * 8;
    v8h v;
    #pragma unroll
    for (int j = 0; j < 8; ++j) v[j] = (_Float16)src[j];
    *(v8h*)(xTf + (((long)s * 128 + mc) * 32 + l) * 8) = v;
    if (s == 0) *(v8h*)(act0a + ((long)mc * 18 + 16) * 512 + l * 8) = v;
}

extern "C" void kernel_launch(void* const* d_in, const int* in_sizes, int n_in,
                              void* d_out, int out_size, void* d_ws, size_t ws_size,
                              hipStream_t stream)
{
    const float* x    = (const float*)d_in[0];
    const float* Wih0 = (const float*)d_in[1];
    const float* Whh0 = (const float*)d_in[2];
    const float* b0   = (const float*)d_in[3];
    const float* Wih1 = (const float*)d_in[4];
    const float* Whh1 = (const float*)d_in[5];
    const float* b1   = (const float*)d_in[6];
    const float* dWih = (const float*)d_in[7];
    const float* dWhh = (const float*)d_in[8];
    const float* db   = (const float*)d_in[9];
    const float* gW1  = (const float*)d_in[10];
    const float* gb1  = (const float*)d_in[11];
    const float* gW2  = (const float*)d_in[12];
    const float* gb2  = (const float*)d_in[13];
    const float* tW1  = (const float*)d_in[14];
    const float* tb1  = (const float*)d_in[15];
    const float* tW2  = (const float*)d_in[16];
    const float* tb2  = (const float*)d_in[17];
    const float* iW1  = (const float*)d_in[18];
    const float* ib1  = (const float*)d_in[19];
    const float* iW2  = (const float*)d_in[20];
    const float* ib2  = (const float*)d_in[21];
    const float* wW1  = (const float*)d_in[22];
    const float* wb1  = (const float*)d_in[23];
    const float* wW2  = (const float*)d_in[24];
    const float* wb2  = (const float*)d_in[25];
    float* out = (float*)d_out;

    char* p = (char*)d_ws;
    auto alloc = [&](size_t bytes) { char* r = p; p += (bytes + 255) & ~255ULL; return r; };
    _Float16* xTf   = (_Float16*)alloc((size_t)SEQ * 128 * 32 * 8 * 2);
    _Float16* act0a = (_Float16*)alloc((size_t)128 * 18 * 512 * 2);
    _Float16* act0b = (_Float16*)alloc((size_t)128 * 18 * 512 * 2);
    _Float16* act1a = (_Float16*)alloc((size_t)128 * 32 * 512 * 2);
    _Float16* act1b = (_Float16*)alloc((size_t)128 * 32 * 512 * 2);
    _Float16* actDa = (_Float16*)alloc((size_t)128 * 18 * 512 * 2);
    _Float16* actDb = (_Float16*)alloc((size_t)128 * 18 * 512 * 2);
    float*    c0    = (float*)alloc((size_t)B_SZ * 512 * 4);
    float*    c1    = (float*)alloc((size_t)B_SZ * 512 * 4);
    _Float16* Wc0   = (_Float16*)alloc((size_t)128 * 18 * 512 * 2);
    _Float16* Wc1   = (_Float16*)alloc((size_t)128 * 32 * 512 * 2);
    _Float16* Wcd   = (_Float16*)alloc((size_t)128 * 18 * 512 * 2);
    float*    b0i   = (float*)alloc((size_t)G4 * 4);
    float*    b1i   = (float*)alloc((size_t)G4 * 4);
    float*    bdi   = (float*)alloc((size_t)G4 * 4);
    _Float16* W1all = (_Float16*)alloc((size_t)25 * 16 * 16 * 512 * 2);
    float*    b1all = (float*)alloc((size_t)25 * HH * 4);
    float*    W2all = (float*)alloc((size_t)24 * 2 * 256 * 4);
    _Float16* t1    = (_Float16*)alloc((size_t)B_SZ * HH * 2);
    float*    pe    = (float*)alloc((size_t)2 * 24 * 2 * 2048 * 4);

    hipMemsetAsync(act0a, 0, (size_t)128 * 18 * 512 * 2, stream);
    hipMemsetAsync(act0b, 0, (size_t)128 * 18 * 512 * 2, stream);
    hipMemsetAsync(act1a, 0, (size_t)128 * 32 * 512 * 2, stream);
    hipMemsetAsync(act1b, 0, (size_t)128 * 32 * 512 * 2, stream);
    hipMemsetAsync(actDa, 0, (size_t)128 * 18 * 512 * 2, stream);
    hipMemsetAsync(actDb, 0, (size_t)128 * 18 * 512 * 2, stream);
    hipMemsetAsync(c0, 0, (size_t)B_SZ * 512 * 4, stream);
    hipMemsetAsync(c1, 0, (size_t)B_SZ * 512 * 4, stream);

    prep_wfrag<<<dim3(128, 18), dim3(64), 0, stream>>>(Whh0, 512, Wih0, 16, Wc0, 18, b0, b0i);
    prep_wfrag<<<dim3(128, 32), dim3(64), 0, stream>>>(Wih1, 512, Whh1, 512, Wc1, 32, b1, b1i);
    prep_wfrag<<<dim3(128, 18), dim3(64), 0, stream>>>(dWhh, 512, dWih, 4, Wcd, 18, db, bdi);
    prep_w1frag<<<dim3(256, 25), dim3(64), 0, stream>>>(tW1, iW1, wW1, gW1, W1all);
    cat4<<<dim3(25), dim3(256), 0, stream>>>(tb1, ib1, wb1, gb1, b1all);
    prep_w2<<<dim3(48), dim3(256), 0, stream>>>(tW2, iW2, wW2, W2all);
    prep_xf<<<dim3(1024), dim3(256), 0, stream>>>(x, xTf, act0a);

    _Float16* act0[2] = {act0a, act0b};
    _Float16* act1[2] = {act1a, act1b};

    // ----- encoder: merged launch s runs L0_s and L1_{s-1} -----
    for (int s = 0; s <= SEQ; ++s) {
        const bool do0 = (s < SEQ), do1 = (s >= 1);
        CellP P0 = {}, P1 = {};
        if (do0) {
            P0.Af = act0[s & 1]; P0.KTA = 18;
            P0.Bf = Wc0; P0.bias = b0i; P0.KT = 18;
            P0.cst = c0;
            P0.h1p = act0[(s + 1) & 1]; P0.h1kt = 18; P0.h1o = 0;
            P0.h2p = act1[s & 1]; P0.h2kt = 32; P0.h2o = 0;
            P0.xsrc = (s < SEQ - 1) ? (xTf + ((long)(s + 1) * 128 * 32) * 8) : nullptr;
            P0.xdst = act0[(s + 1) & 1];
        }
        if (do1) {
            P1.Af = act1[(s + 1) & 1]; P1.KTA = 32;
            P1.Bf = Wc1; P1.bias = b1i; P1.KT = 32;
            P1.cst = c1;
            P1.h1p = act1[s & 1]; P1.h1kt = 32; P1.h1o = 512;
            P1.h2p = (s == SEQ) ? actDa : nullptr; P1.h2kt = 18; P1.h2o = 0;
            P1.xsrc = nullptr; P1.xdst = nullptr;
        }
        const int nz = (do0 && do1) ? 2 : 1;
        const int zbase = do0 ? 0 : 1;
        cell2_k<<<dim3(16, 16, nz), dim3(256), 0, stream>>>(P0, P1, zbase);
    }

    // ----- decoder: 8 steps x 3 launches -----
    for (int t = 0; t < HOR; ++t) {
        _Float16* dr = (t & 1) ? actDb : actDa;
        _Float16* dw = (t & 1) ? actDa : actDb;
        CellP PD = {};
        PD.Af = dr; PD.KTA = 18;
        PD.Bf = Wcd; PD.bias = bdi; PD.KT = 18;
        PD.cst = c1;
        PD.h1p = dw; PD.h1kt = 18; PD.h1o = 0;
        PD.h2p = nullptr; PD.xsrc = nullptr; PD.xdst = nullptr;
        cell2_k<<<dim3(16, 16, 1), dim3(256), 0, stream>>>(PD, PD, 0);
        expert_k<<<dim3(2, 16, 25), dim3(256), 0, stream>>>(dw, W1all, b1all, W2all, pe, t1);
        fin_k<<<dim3(8), dim3(256), 0, stream>>>(t1, gW2, gb2, pe, tb2, ib2, wb2, out, dw, t);
    }
}